// Round 7
// baseline (403.782 us; speedup 1.0000x reference)
//
#include <hip/hip_runtime.h>

#define N_NODES 50000
#define N_EDGES 800000
#define D 64
#define FINE_SHIFT 6
#define NBUCK 782          // 64-node buckets
#define CAP 1280           // max records per bucket (mean 1024 + 8 sigma)
#define SEGCAP 64          // max records per (block,bucket) segment (mean 10.5)
#define EPB 8192
#define NPARTB 98          // partition blocks
#define NMMB 158           // matmul blocks (2 tiles each, 316 >= 196)
#define NTILE 196          // 196*256 = 50176 rows
#define NBLK 256           // total blocks == CUs -> co-resident (capacity 512)
#define NSTART (NBUCK + 1)
#define WS_POISON 0xAAAAAAAAu   // harness poisons d_ws with 0xAA bytes each call

typedef _Float16 f16;
typedef __attribute__((ext_vector_type(4))) _Float16 f16x4;
typedef __attribute__((ext_vector_type(8))) _Float16 f16x8;
typedef __attribute__((ext_vector_type(4))) float f32x4;

#define SMEM_SZ 46080      // matmul overlay is the max: 64*72*2 + 256*72*2

// Software grid barrier on a poison-offset counter. Co-residency guaranteed
// by capacity (2 blocks/CU >= grid/NCU). Replay-safe: stale counter => both
// targets already satisfied => instant pass, never a hang.
__device__ __forceinline__ void grid_sync(unsigned int* bar, unsigned int target) {
    __threadfence();               // agent-scope release (L2 writeback cross-XCD)
    __syncthreads();
    if (threadIdx.x == 0) {
        atomicAdd(bar, 1u);
        while ((unsigned)(atomicAdd(bar, 0u) - WS_POISON) < target)
            __builtin_amdgcn_s_sleep(4);
    }
    __syncthreads();
    __threadfence();               // acquire side
}

__global__ __launch_bounds__(1024) void gcn_mega(
    const int* __restrict__ src, const int* __restrict__ dst,
    unsigned int* __restrict__ binned2, int* __restrict__ starts2,
    unsigned int* __restrict__ bar,
    const float* __restrict__ W, const float* __restrict__ x,
    f16* __restrict__ xwh, const float* __restrict__ b,
    float* __restrict__ out)
{
    __shared__ __align__(16) unsigned char smem[SMEM_SZ];
    const int tid = threadIdx.x;
    const int bid = blockIdx.x;
    const int wave = tid >> 6, lane = tid & 63;

    // ======================= PHASE 1: partition | matmul ====================
    if (bid >= NPARTB) {
        // ---- matmul role: xwh = fp16(x @ W), 2 tiles of 256 rows ----------
        f16 (*WtH)[72]  = (f16 (*)[72])smem;                  // 64 x 72
        f16 (*park)[72] = (f16 (*)[72])(smem + 64 * 72 * 2);  // 256 x 72
        for (int j = tid; j < 4096; j += 1024)
            WtH[j & 63][j >> 6] = (f16)W[j];
        __syncthreads();
        int m = lane & 15, q = lane >> 4;
        for (int k = 0; k < 2; ++k) {
            int t = (bid - NPARTB) + NMMB * k;
            if (t >= NTILE) break;                 // uniform per block
            int nb = t * 256;
            int ar = nb + wave * 16 + m;
            if (ar >= N_NODES) ar = N_NODES - 1;   // clamped; stores guarded
            const float4* x4 = (const float4*)x;
            size_t rb = (size_t)ar * 16;
            float4 p0 = x4[rb + q * 2];
            float4 p1 = x4[rb + q * 2 + 1];
            float4 p2 = x4[rb + 8 + q * 2];
            float4 p3 = x4[rb + 8 + q * 2 + 1];
            f16x8 a0 = { (f16)p0.x, (f16)p0.y, (f16)p0.z, (f16)p0.w,
                         (f16)p1.x, (f16)p1.y, (f16)p1.z, (f16)p1.w };
            f16x8 a1 = { (f16)p2.x, (f16)p2.y, (f16)p2.z, (f16)p2.w,
                         (f16)p3.x, (f16)p3.y, (f16)p3.z, (f16)p3.w };
            f32x4 acc[4];
            #pragma unroll
            for (int t4 = 0; t4 < 4; ++t4) {
                int n0 = t4 * 16;
                f16x8 b0 = *(const f16x8*)&WtH[n0 + m][q * 8];
                f16x8 b1 = *(const f16x8*)&WtH[n0 + m][32 + q * 8];
                f32x4 z = { 0.f, 0.f, 0.f, 0.f };
                z = __builtin_amdgcn_mfma_f32_16x16x32_f16(a0, b0, z, 0, 0, 0);
                acc[t4] = __builtin_amdgcn_mfma_f32_16x16x32_f16(a1, b1, z, 0, 0, 0);
            }
            #pragma unroll
            for (int t4 = 0; t4 < 4; ++t4) {
                int n0 = t4 * 16;
                #pragma unroll
                for (int r = 0; r < 4; ++r)
                    park[wave * 16 + q * 4 + r][n0 + m] = (f16)acc[t4][r];
            }
            __syncthreads();
            for (int j = tid; j < 2048; j += 1024) {
                int row = j >> 3, seg = (j & 7) * 8;
                int n = nb + row;
                if (n < N_NODES)
                    *(f16x8*)&xwh[(size_t)n * D + seg] = *(const f16x8*)&park[row][seg];
            }
            __syncthreads();
        }
    } else {
        // ---- partition role: private bins, LDS-only atomics (proven) ------
        int* hist            = (int*)smem;                    // 782
        int* start_s         = (int*)(smem + 3128);           // 782
        unsigned int* staged = (unsigned int*)(smem + 6256);  // 8192

        int eb  = bid * EPB;
        int total = N_EDGES - eb; if (total > EPB) total = EPB;  // 8192 or 5376

        for (int i = tid; i < NBUCK; i += 1024) hist[i] = 0;
        __syncthreads();

        unsigned int rec[8];
        int rank[8];
        int jb = tid * 8;
        if (jb < total) {
            int4 s0 = *(const int4*)&src[eb + jb];
            int4 s1 = *(const int4*)&src[eb + jb + 4];
            int4 d0 = *(const int4*)&dst[eb + jb];
            int4 d1 = *(const int4*)&dst[eb + jb + 4];
            rec[0] = ((unsigned)d0.x << 16) | (unsigned)s0.x;
            rec[1] = ((unsigned)d0.y << 16) | (unsigned)s0.y;
            rec[2] = ((unsigned)d0.z << 16) | (unsigned)s0.z;
            rec[3] = ((unsigned)d0.w << 16) | (unsigned)s0.w;
            rec[4] = ((unsigned)d1.x << 16) | (unsigned)s1.x;
            rec[5] = ((unsigned)d1.y << 16) | (unsigned)s1.y;
            rec[6] = ((unsigned)d1.z << 16) | (unsigned)s1.z;
            rec[7] = ((unsigned)d1.w << 16) | (unsigned)s1.w;
            #pragma unroll
            for (int u = 0; u < 8; ++u)
                rank[u] = atomicAdd(&hist[rec[u] >> (16 + FINE_SHIFT)], 1);
        } else {
            #pragma unroll
            for (int u = 0; u < 8; ++u) rec[u] = 0xFFFFFFFFu;
        }
        __syncthreads();

        if (tid < 64) {                       // exclusive scan, 13 buckets/lane
            int b0 = tid * 13;
            int v[13]; int run = 0;
            #pragma unroll
            for (int j = 0; j < 13; ++j) {
                int idx = b0 + j;
                int c = (idx < NBUCK) ? hist[idx] : 0;
                v[j] = run; run += c;
            }
            int s = run;
            #pragma unroll
            for (int off = 1; off < 64; off <<= 1) {
                int t = __shfl_up(s, off);
                if (tid >= off) s += t;
            }
            int excl = s - run;
            #pragma unroll
            for (int j = 0; j < 13; ++j) {
                int idx = b0 + j;
                if (idx < NBUCK) start_s[idx] = excl + v[j];
            }
        }
        __syncthreads();

        #pragma unroll
        for (int u = 0; u < 8; ++u) {
            unsigned int v = rec[u];
            if (v != 0xFFFFFFFFu)
                staged[start_s[v >> 22] + rank[u]] = v;
        }
        __syncthreads();

        for (int i = tid; i < total; i += 1024)
            binned2[(size_t)bid * EPB + i] = staged[i];
        for (int i = tid; i < NBUCK; i += 1024)
            starts2[(size_t)bid * NSTART + i] = start_s[i];
        if (tid == 0)
            starts2[(size_t)bid * NSTART + NBUCK] = total;
    }

    grid_sync(bar, NBLK);

    // ============ PHASE 2: ingest-to-LDS + degree + xwh pre-scale ===========
    unsigned int*  srec    = (unsigned int*)smem;              // [4][CAP]
    int*           hists   = (int*)(smem + 20480);             // [4][64]
    int*           segcnt  = (int*)(smem + 21504);             // [128]
    int*           segbase = (int*)(smem + 22016);             // [128]
    int*           segsrc  = (int*)(smem + 22528);             // [98..128]
    int*           scnt    = (int*)(smem + 23040);             // [4]
    unsigned short* ssrc   = (unsigned short*)(smem + 23056);  // [1280]
    int*           off_s   = (int*)(smem + 25616);             // [64]
    int*           cur     = (int*)(smem + 25872);             // [64]

    for (int qq = 0; qq < 4; ++qq) {
        int cb = bid + qq * NBLK;
        if (cb >= NBUCK) break;                 // uniform per block
        if (tid < 64) hists[qq * 64 + tid] = 0;
        int s0r = 0;
        if (tid < NPARTB) {
            int base = tid * NSTART + cb;
            s0r = starts2[base];
            int s1 = starts2[base + 1];
            int c = s1 - s0r; if (c < 0) c = 0; if (c > SEGCAP) c = SEGCAP;
            segcnt[tid] = c;
        }
        __syncthreads();
        if (tid < 64) {                         // blocked scan: lane owns 2 segs
            int b2 = tid * 2;
            int c0 = (b2     < NPARTB) ? segcnt[b2]     : 0;
            int c1 = (b2 + 1 < NPARTB) ? segcnt[b2 + 1] : 0;
            int run = c0 + c1;
            int s = run;
            #pragma unroll
            for (int off = 1; off < 64; off <<= 1) {
                int t = __shfl_up(s, off);
                if (tid >= off) s += t;
            }
            int excl = s - run;
            segbase[b2]     = excl;
            segbase[b2 + 1] = excl + c0;
            if (tid == 63) {
                int tot = excl + run; if (tot > CAP) tot = CAP;
                scnt[qq] = tot;
            }
        }
        __syncthreads();
        if (tid < NPARTB) segsrc[tid] = tid * EPB + s0r - segbase[tid * 2 == tid * 2 ? tid : tid]; // placeholder avoided below
        __syncthreads();
        // NOTE: segbase is indexed per SEGMENT (0..127); rebase properly:
        if (tid < NPARTB) segsrc[tid] = tid * EPB + s0r - segbase[tid];
        __syncthreads();

        int stot = scnt[qq];
        for (int i = tid; i < stot; i += 1024) {   // one round for most buckets
            int lo = 0, hi = 127;
            #pragma unroll
            for (int it = 0; it < 7; ++it) {       // largest s: segbase[s] <= i
                int mid = (lo + hi + 1) >> 1;
                if (segbase[mid] <= i) lo = mid; else hi = mid - 1;
            }
            unsigned int r = binned2[segsrc[lo] + i];
            srec[qq * CAP + i] = r;
            atomicAdd(&hists[qq * 64 + ((r >> 16) & 63)], 1);
        }
        __syncthreads();

        // in-place pre-scale of this bucket's 64 xwh rows (fp32 intermediate)
        int nb = cb * 64;
        for (int j = tid; j < 512; j += 1024) {
            int row = j >> 3, seg = (j & 7) * 8;
            int n = nb + row;
            if (n < N_NODES) {
                float dn = rsqrtf((float)hists[qq * 64 + row] + 1.0f);
                f16x8 v = *(f16x8*)&xwh[(size_t)n * D + seg];
                #pragma unroll
                for (int e = 0; e < 8; ++e)
                    v[e] = (f16)((float)v[e] * dn);
                *(f16x8*)&xwh[(size_t)n * D + seg] = v;
            }
        }
        __syncthreads();
    }

    grid_sync(bar, 2 * NBLK);

    // ================= PHASE 3: gather from LDS-resident records ============
    const f16x4* xw4 = (const f16x4*)xwh;      // row = 16 x f16x4 (pre-scaled)
    const float4* b4p = (const float4*)b;
    float4* out4 = (float4*)out;
    int g = lane >> 4, c16 = lane & 15;

    for (int qq = 0; qq < 4; ++qq) {
        int cb = bid + qq * NBLK;
        if (cb >= NBUCK) break;                 // uniform per block
        int nb = cb * 64;
        int stot = scnt[qq];
        int* h = &hists[qq * 64];

        if (tid < 64) {                         // scan node hist -> offsets
            int v = h[tid], s = v;
            #pragma unroll
            for (int off = 1; off < 64; off <<= 1) {
                int t = __shfl_up(s, off);
                if (tid >= off) s += t;
            }
            off_s[tid] = s - v;
            cur[tid]   = s - v;
        }
        __syncthreads();
        for (int i = tid; i < stot; i += 1024) {   // counting-sort scatter
            unsigned int v = srec[qq * CAP + i];
            int p = atomicAdd(&cur[(v >> 16) & 63], 1);
            ssrc[p] = (unsigned short)(v & 0xFFFFu);
        }
        __syncthreads();

        for (int i = 0; i < 4; ++i) {              // 4 nodes per wave
            int nl = wave * 4 + i;
            int n  = nb + nl;
            if (n >= N_NODES) break;               // wave-uniform
            int off = off_s[nl], c = h[nl];
            float dn = rsqrtf((float)c + 1.0f);    // dis[n]

            float a0 = 0.f, a1 = 0.f, a2 = 0.f, a3 = 0.f;
            if (g == 0) {                          // self term (pre-scaled)
                f16x4 sv = xw4[(size_t)n * 16 + c16];
                a0 = (float)sv.x; a1 = (float)sv.y; a2 = (float)sv.z; a3 = (float)sv.w;
            }
            int k = off + g, e = off + c;
            for (; k + 12 < e; k += 16) {          // 4 records in flight/group
                int s0 = ssrc[k], s1 = ssrc[k + 4], s2 = ssrc[k + 8], s3 = ssrc[k + 12];
                f16x4 v0 = xw4[(size_t)s0 * 16 + c16];
                f16x4 v1 = xw4[(size_t)s1 * 16 + c16];
                f16x4 v2 = xw4[(size_t)s2 * 16 + c16];
                f16x4 v3 = xw4[(size_t)s3 * 16 + c16];
                a0 += (float)v0.x + (float)v1.x + (float)v2.x + (float)v3.x;
                a1 += (float)v0.y + (float)v1.y + (float)v2.y + (float)v3.y;
                a2 += (float)v0.z + (float)v1.z + (float)v2.z + (float)v3.z;
                a3 += (float)v0.w + (float)v1.w + (float)v2.w + (float)v3.w;
            }
            for (; k + 4 < e; k += 8) {
                int s0 = ssrc[k], s1 = ssrc[k + 4];
                f16x4 v0 = xw4[(size_t)s0 * 16 + c16];
                f16x4 v1 = xw4[(size_t)s1 * 16 + c16];
                a0 += (float)v0.x + (float)v1.x;
                a1 += (float)v0.y + (float)v1.y;
                a2 += (float)v0.z + (float)v1.z;
                a3 += (float)v0.w + (float)v1.w;
            }
            if (k < e) {
                f16x4 v = xw4[(size_t)ssrc[k] * 16 + c16];
                a0 += (float)v.x; a1 += (float)v.y; a2 += (float)v.z; a3 += (float)v.w;
            }
            a0 += __shfl_xor(a0, 32); a1 += __shfl_xor(a1, 32);
            a2 += __shfl_xor(a2, 32); a3 += __shfl_xor(a3, 32);
            a0 += __shfl_xor(a0, 16); a1 += __shfl_xor(a1, 16);
            a2 += __shfl_xor(a2, 16); a3 += __shfl_xor(a3, 16);
            if (g == 0) {
                float4 bl = b4p[c16];
                float4 r;
                r.x = fmaxf(bl.x + dn * a0, 0.f);
                r.y = fmaxf(bl.y + dn * a1, 0.f);
                r.z = fmaxf(bl.z + dn * a2, 0.f);
                r.w = fmaxf(bl.w + dn * a3, 0.f);
                out4[(size_t)n * 16 + c16] = r;
            }
        }
        __syncthreads();
    }
}

// ---------------------------------------------------------------------------
extern "C" void kernel_launch(void* const* d_in, const int* in_sizes, int n_in,
                              void* d_out, int out_size, void* d_ws, size_t ws_size,
                              hipStream_t stream) {
    const float* x  = (const float*)d_in[0];
    const int*   ei = (const int*)d_in[1];   // [2, E] flat: src then dst
    const float* W  = (const float*)d_in[2];
    const float* b  = (const float*)d_in[3];

    const int* src = ei;
    const int* dst = ei + N_EDGES;
    float* out = (float*)d_out;

    // ws: xwh (6.4MB) | binned2 (3.2MB) | starts2 (307KB) | bar (4B)
    f16*          xwh     = (f16*)d_ws;
    unsigned int* binned2 = (unsigned int*)(xwh + (size_t)N_NODES * D);
    int*          starts2 = (int*)(binned2 + (size_t)NPARTB * EPB);
    unsigned int* bar     = (unsigned int*)(starts2 + (size_t)NPARTB * NSTART);

    gcn_mega<<<NBLK, 1024, 0, stream>>>(
        src, dst, binned2, starts2, bar, W, x, xwh, b, out);
}

// Round 8
// 108.535 us; speedup vs baseline: 3.7203x; 3.7203x over previous
//
#include <hip/hip_runtime.h>

#define N_NODES 50000
#define N_EDGES 800000
#define D 64
#define FINE_SHIFT 6
#define NBUCK 782          // 64-node buckets
#define CAP 1280           // max records per bucket (mean 1024 + 8 sigma)
#define SEGCAP 64          // max per (block,bucket) segment (mean 5.2)
#define EPB 4096           // edges per partition block (was 8192)
#define NPART 196          // partition blocks (2x parallelism)
#define NMM 196            // matmul blocks: 196*256 = 50176 rows
#define NSTART (NBUCK + 1) // per-block starts table entries

typedef _Float16 f16;
typedef __attribute__((ext_vector_type(4))) _Float16 f16x4;
typedef __attribute__((ext_vector_type(8))) _Float16 f16x8;
typedef __attribute__((ext_vector_type(4))) float f32x4;

#define SMEM_PART (2 * NBUCK * 4 + EPB * 4)      // 22640 B
#define SMEM_MM   (64 * 72 * 2 + 256 * 72 * 2)   // 46080 B
#define SMEM_SZ   (SMEM_MM > SMEM_PART ? SMEM_MM : SMEM_PART)

// ---------------------------------------------------------------------------
// K1: fused launch, ZERO global atomics. Blocks [0,196): edge partition into
// private per-block bins — 4096 edges each (halved: partition was the 45µs
// latency-bound critical path at 98 blocks / 19% residency). Blocks
// [196,392): independent x@W matmul. ~2 blocks/CU -> 32 waves of hiding.
// ---------------------------------------------------------------------------
__global__ __launch_bounds__(1024) void partition_matmul(
    const int* __restrict__ src, const int* __restrict__ dst,
    unsigned int* __restrict__ binned2, int* __restrict__ starts2,
    const float* __restrict__ W, const float* __restrict__ x,
    f16* __restrict__ xwh)
{
    __shared__ __align__(16) unsigned char smem[SMEM_SZ];
    int tid = threadIdx.x;

    if (blockIdx.x >= NPART) {
        // ---------------- matmul role: xwh = fp16(x @ W) -------------------
        f16 (*WtH)[72]  = (f16 (*)[72])smem;                  // 64 x 72
        f16 (*park)[72] = (f16 (*)[72])(smem + 64 * 72 * 2);  // 256 x 72

        for (int j = tid; j < 4096; j += 1024)
            WtH[j & 63][j >> 6] = (f16)W[j];
        __syncthreads();

        int nb = (blockIdx.x - NPART) * 256;
        int wave = tid >> 6, lane = tid & 63;
        int m = lane & 15, q = lane >> 4;

        int ar = nb + wave * 16 + m;
        if (ar >= N_NODES) ar = N_NODES - 1;   // clamped; stores guarded
        const float4* x4 = (const float4*)x;
        size_t rb = (size_t)ar * 16;
        float4 p0 = x4[rb + q * 2];
        float4 p1 = x4[rb + q * 2 + 1];
        float4 p2 = x4[rb + 8 + q * 2];
        float4 p3 = x4[rb + 8 + q * 2 + 1];
        f16x8 a0 = { (f16)p0.x, (f16)p0.y, (f16)p0.z, (f16)p0.w,
                     (f16)p1.x, (f16)p1.y, (f16)p1.z, (f16)p1.w };
        f16x8 a1 = { (f16)p2.x, (f16)p2.y, (f16)p2.z, (f16)p2.w,
                     (f16)p3.x, (f16)p3.y, (f16)p3.z, (f16)p3.w };

        f32x4 acc[4];
        #pragma unroll
        for (int t = 0; t < 4; ++t) {
            int n0 = t * 16;
            f16x8 b0 = *(const f16x8*)&WtH[n0 + m][q * 8];
            f16x8 b1 = *(const f16x8*)&WtH[n0 + m][32 + q * 8];
            f32x4 z = { 0.f, 0.f, 0.f, 0.f };
            z = __builtin_amdgcn_mfma_f32_16x16x32_f16(a0, b0, z, 0, 0, 0);
            acc[t] = __builtin_amdgcn_mfma_f32_16x16x32_f16(a1, b1, z, 0, 0, 0);
        }

        #pragma unroll
        for (int t = 0; t < 4; ++t) {
            int n0 = t * 16;
            #pragma unroll
            for (int r = 0; r < 4; ++r)
                park[wave * 16 + q * 4 + r][n0 + m] = (f16)acc[t][r];
        }
        __syncthreads();

        for (int j = tid; j < 2048; j += 1024) {
            int row = j >> 3, seg = (j & 7) * 8;
            int n = nb + row;
            if (n < N_NODES)
                *(f16x8*)&xwh[(size_t)n * D + seg] = *(const f16x8*)&park[row][seg];
        }
        return;
    }

    // ---------------- partition role: private bins, no atomics -------------
    int* hist            = (int*)smem;
    int* start_s         = hist + NBUCK;
    unsigned int* staged = (unsigned int*)(start_s + NBUCK);

    int eb  = blockIdx.x * EPB;
    int total = N_EDGES - eb; if (total > EPB) total = EPB;  // 4096 or 1280

    for (int i = tid; i < NBUCK; i += 1024) hist[i] = 0;
    __syncthreads();

    unsigned int rec[4];
    int rank[4];
    int jb = tid * 4;
    if (jb < total) {
        int4 s0 = *(const int4*)&src[eb + jb];
        int4 d0 = *(const int4*)&dst[eb + jb];
        rec[0] = ((unsigned)d0.x << 16) | (unsigned)s0.x;
        rec[1] = ((unsigned)d0.y << 16) | (unsigned)s0.y;
        rec[2] = ((unsigned)d0.z << 16) | (unsigned)s0.z;
        rec[3] = ((unsigned)d0.w << 16) | (unsigned)s0.w;
        #pragma unroll
        for (int u = 0; u < 4; ++u)
            rank[u] = atomicAdd(&hist[rec[u] >> (16 + FINE_SHIFT)], 1);  // LDS only
    } else {
        #pragma unroll
        for (int u = 0; u < 4; ++u) rec[u] = 0xFFFFFFFFu;
    }
    __syncthreads();

    // exclusive scan of hist[0..781] by wave 0 (13 buckets per lane)
    if (tid < 64) {
        int b0 = tid * 13;
        int v[13]; int run = 0;
        #pragma unroll
        for (int j = 0; j < 13; ++j) {
            int idx = b0 + j;
            int c = (idx < NBUCK) ? hist[idx] : 0;
            v[j] = run; run += c;
        }
        int s = run;
        #pragma unroll
        for (int off = 1; off < 64; off <<= 1) {
            int t = __shfl_up(s, off);
            if (tid >= off) s += t;
        }
        int excl = s - run;
        #pragma unroll
        for (int j = 0; j < 13; ++j) {
            int idx = b0 + j;
            if (idx < NBUCK) start_s[idx] = excl + v[j];
        }
    }
    __syncthreads();

    // place records into bucket-grouped LDS order using histogram ranks
    #pragma unroll
    for (int u = 0; u < 4; ++u) {
        unsigned int v = rec[u];
        if (v != 0xFFFFFFFFu)
            staged[start_s[v >> 22] + rank[u]] = v;
    }
    __syncthreads();

    // linear, fully coalesced write-out of the private bin + starts table
    for (int i = tid; i < total; i += 1024)
        binned2[(size_t)blockIdx.x * EPB + i] = staged[i];
    for (int i = tid; i < NBUCK; i += 1024)
        starts2[(size_t)blockIdx.x * NSTART + i] = start_s[i];
    if (tid == 0)
        starts2[(size_t)blockIdx.x * NSTART + NBUCK] = total;
}

// ---------------------------------------------------------------------------
// K2: degree + in-place dis pre-scale of xwh (proven R6 math). Flattened
// segmented ingest over 196 segments (binary search, one load per record,
// full lanes), bucket histogram, xwh[n] *= rsqrt(deg_n+1) for 64 rows.
// ---------------------------------------------------------------------------
__global__ __launch_bounds__(256) void degree_scale(
    const unsigned int* __restrict__ binned2, const int* __restrict__ starts2,
    f16* __restrict__ xwh)
{
    __shared__ int segcnt_s[NPART], segbase_s[NPART], segsrc_s[NPART];
    __shared__ int h[64];
    __shared__ int stot_s;

    int cb = blockIdx.x, tid = threadIdx.x;
    if (tid < 64) h[tid] = 0;
    if (tid < NPART) {
        int base = tid * NSTART + cb;
        int s0 = starts2[base], s1 = starts2[base + 1];
        int c = s1 - s0; if (c < 0) c = 0; if (c > SEGCAP) c = SEGCAP;
        segcnt_s[tid] = c;
        segsrc_s[tid] = tid * EPB + s0;    // absolute; rebased after scan
    }
    __syncthreads();

    // scan of 196 segment counts: wave 0, 4 segments per lane
    if (tid < 64) {
        int c[4]; int run = 0;
        #pragma unroll
        for (int j = 0; j < 4; ++j) {
            int idx = tid * 4 + j;
            c[j] = run;
            run += (idx < NPART) ? segcnt_s[idx] : 0;
        }
        int s = run;
        #pragma unroll
        for (int off = 1; off < 64; off <<= 1) {
            int t = __shfl_up(s, off);
            if (tid >= off) s += t;
        }
        int excl = s - run;
        #pragma unroll
        for (int j = 0; j < 4; ++j) {
            int idx = tid * 4 + j;
            if (idx < NPART) segbase_s[idx] = excl + c[j];
        }
        if (tid == 63) {
            int tot = excl + run; if (tot > CAP) tot = CAP;
            stot_s = tot;
        }
    }
    __syncthreads();
    if (tid < NPART) segsrc_s[tid] -= segbase_s[tid];
    __syncthreads();

    int stot = stot_s;
    for (int i = tid; i < stot; i += 256) {
        int lo = 0, hi = NPART - 1;
        #pragma unroll
        for (int it = 0; it < 8; ++it) {       // largest s: segbase[s] <= i
            int mid = (lo + hi + 1) >> 1;
            if (segbase_s[mid] <= i) lo = mid; else hi = mid - 1;
        }
        unsigned int r = binned2[segsrc_s[lo] + i];
        atomicAdd(&h[(r >> 16) & 63], 1);
    }
    __syncthreads();

    // in-place pre-scale: xwh[n] = dis_n * xw[n]  (fp32 intermediate)
    int nb = cb * 64;
    for (int j = tid; j < 512; j += 256) {     // 64 rows x 8 chunks
        int row = j >> 3, seg = (j & 7) * 8;
        int n = nb + row;
        if (n < N_NODES) {
            float dn = rsqrtf((float)h[row] + 1.0f);
            f16x8 v = *(f16x8*)&xwh[(size_t)n * D + seg];
            #pragma unroll
            for (int e = 0; e < 8; ++e)
                v[e] = (f16)((float)v[e] * dn);
            *(f16x8*)&xwh[(size_t)n * D + seg] = v;
        }
    }
}

// ---------------------------------------------------------------------------
// K3: gather, pure-sum inner loop (xwh pre-scaled by dis). Flattened
// segmented ingest of binned2 (196 segments), LDS counting-sort,
// wave-per-node with f16x4 chunks, 4 records in flight per 16-lane group.
// ---------------------------------------------------------------------------
__global__ __launch_bounds__(512) void gather_out(
    const unsigned int* __restrict__ binned2, const int* __restrict__ starts2,
    const f16* __restrict__ xwh, const float* __restrict__ b,
    float* __restrict__ out)
{
    __shared__ unsigned short ssrc[CAP];
    __shared__ int h[64], off_s[64], cur[64];
    __shared__ int segcnt_s[NPART], segbase_s[NPART], segsrc_s[NPART];
    __shared__ int stot_s;

    int cb = blockIdx.x, tid = threadIdx.x;
    int wave = tid >> 6, lane = tid & 63;
    int nb = cb * 64;

    if (tid < 64) h[tid] = 0;
    if (tid < NPART) {
        int base = tid * NSTART + cb;
        int s0 = starts2[base], s1 = starts2[base + 1];
        int c = s1 - s0; if (c < 0) c = 0; if (c > SEGCAP) c = SEGCAP;
        segcnt_s[tid] = c;
        segsrc_s[tid] = tid * EPB + s0;    // absolute; rebased after scan
    }
    __syncthreads();

    // scan of 196 segment counts: wave 0, 4 segments per lane
    if (tid < 64) {
        int c[4]; int run = 0;
        #pragma unroll
        for (int j = 0; j < 4; ++j) {
            int idx = tid * 4 + j;
            c[j] = run;
            run += (idx < NPART) ? segcnt_s[idx] : 0;
        }
        int s = run;
        #pragma unroll
        for (int off = 1; off < 64; off <<= 1) {
            int t = __shfl_up(s, off);
            if (tid >= off) s += t;
        }
        int excl = s - run;
        #pragma unroll
        for (int j = 0; j < 4; ++j) {
            int idx = tid * 4 + j;
            if (idx < NPART) segbase_s[idx] = excl + c[j];
        }
        if (tid == 63) {
            int tot = excl + run; if (tot > CAP) tot = CAP;
            stot_s = tot;
        }
    }
    __syncthreads();
    if (tid < NPART) segsrc_s[tid] -= segbase_s[tid];
    __syncthreads();

    int cnt = stot_s;
    unsigned int rec[3];
    #pragma unroll
    for (int u = 0; u < 3; ++u) {
        int j = u * 512 + tid;
        if (j < cnt) {
            int lo = 0, hi = NPART - 1;
            #pragma unroll
            for (int it = 0; it < 8; ++it) {   // largest s: segbase[s] <= j
                int mid = (lo + hi + 1) >> 1;
                if (segbase_s[mid] <= j) lo = mid; else hi = mid - 1;
            }
            rec[u] = binned2[segsrc_s[lo] + j];
            atomicAdd(&h[(rec[u] >> 16) & 63], 1);
        } else rec[u] = 0xFFFFFFFFu;
    }
    __syncthreads();

    if (tid < 64) {
        int v = h[tid], s = v;
        #pragma unroll
        for (int off = 1; off < 64; off <<= 1) {
            int t = __shfl_up(s, off);
            if (tid >= off) s += t;
        }
        off_s[tid] = s - v;
        cur[tid]   = s - v;
    }
    __syncthreads();

    #pragma unroll
    for (int u = 0; u < 3; ++u) {
        unsigned int v = rec[u];
        if (v != 0xFFFFFFFFu) {
            int p = atomicAdd(&cur[(v >> 16) & 63], 1);
            ssrc[p] = (unsigned short)(v & 0xFFFFu);
        }
    }
    __syncthreads();

    const f16x4* xw4 = (const f16x4*)xwh;      // row = 16 x f16x4 (pre-scaled)
    const float4* b4p = (const float4*)b;
    float4* out4 = (float4*)out;               // row = 16 x float4
    int g = lane >> 4, c16 = lane & 15;

    for (int i = 0; i < 8; ++i) {
        int nl = wave * 8 + i;
        int n  = nb + nl;
        if (n >= N_NODES) break;               // wave-uniform
        int off = off_s[nl], c = h[nl];
        float dn = rsqrtf((float)c + 1.0f);    // dis[n]

        float a0 = 0.f, a1 = 0.f, a2 = 0.f, a3 = 0.f;
        if (g == 0) {                          // self term (already dis_n-scaled)
            f16x4 sv = xw4[(size_t)n * 16 + c16];
            a0 = (float)sv.x; a1 = (float)sv.y; a2 = (float)sv.z; a3 = (float)sv.w;
        }
        int k = off + g, e = off + c;
        for (; k + 12 < e; k += 16) {          // 4 records per group in flight
            int s0 = ssrc[k], s1 = ssrc[k + 4], s2 = ssrc[k + 8], s3 = ssrc[k + 12];
            f16x4 v0 = xw4[(size_t)s0 * 16 + c16];
            f16x4 v1 = xw4[(size_t)s1 * 16 + c16];
            f16x4 v2 = xw4[(size_t)s2 * 16 + c16];
            f16x4 v3 = xw4[(size_t)s3 * 16 + c16];
            a0 += (float)v0.x + (float)v1.x + (float)v2.x + (float)v3.x;
            a1 += (float)v0.y + (float)v1.y + (float)v2.y + (float)v3.y;
            a2 += (float)v0.z + (float)v1.z + (float)v2.z + (float)v3.z;
            a3 += (float)v0.w + (float)v1.w + (float)v2.w + (float)v3.w;
        }
        for (; k + 4 < e; k += 8) {            // 2 records per group
            int s0 = ssrc[k], s1 = ssrc[k + 4];
            f16x4 v0 = xw4[(size_t)s0 * 16 + c16];
            f16x4 v1 = xw4[(size_t)s1 * 16 + c16];
            a0 += (float)v0.x + (float)v1.x;
            a1 += (float)v0.y + (float)v1.y;
            a2 += (float)v0.z + (float)v1.z;
            a3 += (float)v0.w + (float)v1.w;
        }
        if (k < e) {
            f16x4 v = xw4[(size_t)ssrc[k] * 16 + c16];
            a0 += (float)v.x; a1 += (float)v.y; a2 += (float)v.z; a3 += (float)v.w;
        }
        a0 += __shfl_xor(a0, 32); a1 += __shfl_xor(a1, 32);
        a2 += __shfl_xor(a2, 32); a3 += __shfl_xor(a3, 32);
        a0 += __shfl_xor(a0, 16); a1 += __shfl_xor(a1, 16);
        a2 += __shfl_xor(a2, 16); a3 += __shfl_xor(a3, 16);
        if (g == 0) {
            float4 bl = b4p[c16];
            float4 r;
            r.x = fmaxf(bl.x + dn * a0, 0.f);
            r.y = fmaxf(bl.y + dn * a1, 0.f);
            r.z = fmaxf(bl.z + dn * a2, 0.f);
            r.w = fmaxf(bl.w + dn * a3, 0.f);
            out4[(size_t)n * 16 + c16] = r;
        }
    }
}

// ---------------------------------------------------------------------------
extern "C" void kernel_launch(void* const* d_in, const int* in_sizes, int n_in,
                              void* d_out, int out_size, void* d_ws, size_t ws_size,
                              hipStream_t stream) {
    const float* x  = (const float*)d_in[0];
    const int*   ei = (const int*)d_in[1];   // [2, E] flat: src then dst
    const float* W  = (const float*)d_in[2];
    const float* b  = (const float*)d_in[3];

    const int* src = ei;
    const int* dst = ei + N_EDGES;
    float* out = (float*)d_out;

    // ws: xwh (6.4MB) | binned2 (3.2MB) | starts2 (614KB)
    f16*          xwh     = (f16*)d_ws;
    unsigned int* binned2 = (unsigned int*)(xwh + (size_t)N_NODES * D);
    int*          starts2 = (int*)(binned2 + (size_t)NPART * EPB);

    partition_matmul<<<NPART + NMM, 1024, 0, stream>>>(
        src, dst, binned2, starts2, W, x, xwh);
    degree_scale<<<NBUCK, 256, 0, stream>>>(binned2, starts2, xwh);
    gather_out<<<NBUCK, 512, 0, stream>>>(binned2, starts2, xwh, b, out);
}